// Round 5
// baseline (546.468 us; speedup 1.0000x reference)
//
#include <hip/hip_runtime.h>

#define MT 16384   // B*T = 8*2048
#define NT 2048    // OUT
#define KT 2048    // IN
#define BM 128
#define BN 128
#define BK 64

typedef __attribute__((ext_vector_type(8))) short short8;     // 8 bf16 (4 VGPRs) MFMA A/B frag
typedef __attribute__((ext_vector_type(4))) float f32x4;      // MFMA C/D frag
typedef __attribute__((ext_vector_type(8))) unsigned short ushort8;
typedef __attribute__((ext_vector_type(4))) unsigned short ushort4v;

__device__ __forceinline__ unsigned short f32_bf16(float f) {
    union { float f; unsigned u; } v; v.f = f;
    return (unsigned short)((v.u + 0x7FFFu + ((v.u >> 16) & 1u)) >> 16);
}

// ---- merged preconvert: x (fp32->bf16) then w (int32->bf16), one dispatch ----

__global__ __launch_bounds__(256) void cvt_kernel(const float* __restrict__ x,
                                                  const int* __restrict__ w,
                                                  unsigned short* __restrict__ xb,
                                                  unsigned short* __restrict__ wb) {
    const int b = blockIdx.x;
    if (b < MT * KT / 2048) {
        size_t i = ((size_t)b * 256 + threadIdx.x) * 8;
        float4 v0 = *(const float4*)(x + i);
        float4 v1 = *(const float4*)(x + i + 4);
        ushort8 o;
        o[0] = f32_bf16(v0.x); o[1] = f32_bf16(v0.y); o[2] = f32_bf16(v0.z); o[3] = f32_bf16(v0.w);
        o[4] = f32_bf16(v1.x); o[5] = f32_bf16(v1.y); o[6] = f32_bf16(v1.z); o[7] = f32_bf16(v1.w);
        *(ushort8*)(xb + i) = o;
    } else {
        size_t i = ((size_t)(b - MT * KT / 2048) * 256 + threadIdx.x) * 8;
        int4 v0 = *(const int4*)(w + i);
        int4 v1 = *(const int4*)(w + i + 4);
        ushort8 o;
        o[0] = f32_bf16((float)v0.x); o[1] = f32_bf16((float)v0.y);
        o[2] = f32_bf16((float)v0.z); o[3] = f32_bf16((float)v0.w);
        o[4] = f32_bf16((float)v1.x); o[5] = f32_bf16((float)v1.y);
        o[6] = f32_bf16((float)v1.z); o[7] = f32_bf16((float)v1.w);
        *(ushort8*)(wb + i) = o;
    }
}

// ---- GEMM: C[m][n] = sum_k A[m][k] * W[n][k], epilogue *2^s_exp[n] + bias[n] ----
// R5 structure change: B (= W, 8 MB, L2-hot: 512 KB strip reused by 128
// consecutive blocks) bypasses LDS entirely -- fragments loaded straight from
// global into registers with compiler-scheduled fine-grained vmcnt (the AITER
// idiom, expressible in HIP for plain register loads). Only A goes through the
// barrier-fenced global_load_lds staging. LDS reads/writes halve; the
// __syncthreads drain covers only A.
// A LDS layout: [128 rows][8 chunks of 16B], chunk swizzled (R3-verified,
// SQ_LDS_BANK_CONFLICT 1.678e7 -> 0): logical (row,c) at slot row*8+((c+row)&7).

__device__ __forceinline__ int swz(int row, int c) {        // logical chunk -> slot
    return row * 8 + ((c + row) & 7);
}

template <bool PRE>
__global__ __launch_bounds__(256) void gemm_bt(
    const unsigned short* __restrict__ Abf, const unsigned short* __restrict__ Bbf,
    const float* __restrict__ Af32, const int* __restrict__ Wi32,
    const int* __restrict__ sexp, const float* __restrict__ bias,
    float* __restrict__ C)
{
    __shared__ unsigned short As[BM * BK];                 // 16 KB
    __shared__ unsigned short Bs[PRE ? 8 : BN * BK];       // fallback-only B staging

    const int tid  = threadIdx.x;
    const int row0 = blockIdx.x * BM;   // M block (fastest dim -> B strip stays L2-hot)
    const int col0 = blockIdx.y * BN;   // N block
    const int lane = tid & 63;
    const int wave = tid >> 6;
    const int wm = wave >> 1, wn = wave & 1;   // 2x2 waves, each 64x64
    const int q = lane >> 4, r = lane & 15;

    f32x4 acc[4][4] = {};

    // per-lane B row bases: n = col0 + wn*64 + j*16 + r
    const unsigned short* Brow[4];
    if constexpr (PRE) {
        #pragma unroll
        for (int j = 0; j < 4; ++j)
            Brow[j] = Bbf + (size_t)(col0 + wn * 64 + j * 16 + r) * KT + q * 8;
    }

    for (int k0 = 0; k0 < KT; k0 += BK) {
        if constexpr (PRE) {
            // A staging: 1024 x 16B slots; slot s holds logical chunk ((s&7)-row)&7
            // of row s>>3; HW dest = wave-uniform base + lane*16.
            #pragma unroll
            for (int ii = 0; ii < 4; ++ii) {
                const int s   = tid + ii * 256;
                const int row = s >> 3;
                const int cg  = ((s & 7) - row) & 7;
                const unsigned short* ga =
                    Abf + (size_t)(row0 + row) * KT + k0 + cg * 8;
                __builtin_amdgcn_global_load_lds(
                    (const __attribute__((address_space(1))) unsigned int*)ga,
                    (__attribute__((address_space(3))) unsigned int*)(As + (size_t)(ii * 256 + wave * 64) * 8),
                    16, 0, 0);
            }
            __syncthreads();   // drains A staging only (B is register-loaded)

            // B fragments straight from global (L2-hot): element t = B[n][k0+h*32+q*8+t]
            short8 b[2][4];
            #pragma unroll
            for (int h = 0; h < 2; ++h)
                #pragma unroll
                for (int j = 0; j < 4; ++j)
                    b[h][j] = *(const short8*)(Brow[j] + k0 + h * 32);

            #pragma unroll
            for (int h = 0; h < 2; ++h) {
                short8 a[4];
                #pragma unroll
                for (int i = 0; i < 4; ++i)
                    a[i] = *(const short8*)(As + swz(wm * 64 + i * 16 + r, h * 4 + q) * 8);
                #pragma unroll
                for (int i = 0; i < 4; ++i)
                    #pragma unroll
                    for (int j = 0; j < 4; ++j)
                        acc[i][j] = __builtin_amdgcn_mfma_f32_16x16x32_bf16(a[i], b[h][j], acc[i][j], 0, 0, 0);
            }
            __syncthreads();
        } else {
            // fallback (ws too small): fused-conversion staging of BOTH tiles
            #pragma unroll
            for (int ii = 0; ii < 8; ++ii) {
                const int s  = tid + ii * 256;
                const int rw = s >> 4, c4 = s & 15;
                const int ch = c4 >> 1, hf = c4 & 1;
                const int ps = ((ch + rw) & 7) * 8 + hf * 4;
                float4 v = *(const float4*)(Af32 + (size_t)(row0 + rw) * KT + k0 + c4 * 4);
                ushort4v oa;
                oa[0] = f32_bf16(v.x); oa[1] = f32_bf16(v.y);
                oa[2] = f32_bf16(v.z); oa[3] = f32_bf16(v.w);
                *(ushort4v*)(As + rw * BK + ps) = oa;
                int4 w4 = *(const int4*)(Wi32 + (size_t)(col0 + rw) * KT + k0 + c4 * 4);
                ushort4v ob;
                ob[0] = f32_bf16((float)w4.x); ob[1] = f32_bf16((float)w4.y);
                ob[2] = f32_bf16((float)w4.z); ob[3] = f32_bf16((float)w4.w);
                *(ushort4v*)(Bs + rw * BK + ps) = ob;
            }
            __syncthreads();
            #pragma unroll
            for (int h = 0; h < 2; ++h) {
                short8 a[4], b[4];
                #pragma unroll
                for (int i = 0; i < 4; ++i)
                    a[i] = *(const short8*)(As + swz(wm * 64 + i * 16 + r, h * 4 + q) * 8);
                #pragma unroll
                for (int j = 0; j < 4; ++j)
                    b[j] = *(const short8*)(Bs + swz(wn * 64 + j * 16 + r, h * 4 + q) * 8);
                #pragma unroll
                for (int i = 0; i < 4; ++i)
                    #pragma unroll
                    for (int j = 0; j < 4; ++j)
                        acc[i][j] = __builtin_amdgcn_mfma_f32_16x16x32_bf16(a[i], b[j], acc[i][j], 0, 0, 0);
            }
            __syncthreads();
        }
    }

    // epilogue: C/D layout col = lane&15, row = (lane>>4)*4 + reg  [m89/m91-verified]
    #pragma unroll
    for (int j = 0; j < 4; ++j) {
        const int n  = col0 + wn * 64 + j * 16 + r;
        const float sc = ldexpf(1.0f, sexp[n]);   // exact power-of-two scale
        const float bs = bias[n];
        #pragma unroll
        for (int i = 0; i < 4; ++i) {
            const int m = row0 + wm * 64 + i * 16 + q * 4;
            float* cp = C + (size_t)m * NT + n;
            #pragma unroll
            for (int t = 0; t < 4; ++t)
                cp[(size_t)t * NT] = acc[i][j][t] * sc + bs;
        }
    }
}

extern "C" void kernel_launch(void* const* d_in, const int* in_sizes, int n_in,
                              void* d_out, int out_size, void* d_ws, size_t ws_size,
                              hipStream_t stream) {
    const float* x    = (const float*)d_in[0];
    const int*   wq   = (const int*)d_in[1];   // ternary {-1,0,1}, int32 per harness
    const int*   se   = (const int*)d_in[2];   // exponents [-8,0]
    const float* bias = (const float*)d_in[3];
    float* out = (float*)d_out;

    const size_t xb_elems = (size_t)MT * KT;   // 33554432
    const size_t wb_elems = (size_t)NT * KT;   // 4194304
    dim3 grid(MT / BM, NT / BN);               // (128, 16)

    if (ws_size >= (xb_elems + wb_elems) * sizeof(unsigned short)) {
        unsigned short* xb = (unsigned short*)d_ws;
        unsigned short* wb = xb + xb_elems;
        cvt_kernel<<<(int)((xb_elems + wb_elems) / (256 * 8)), 256, 0, stream>>>(x, wq, xb, wb);
        gemm_bt<true><<<grid, 256, 0, stream>>>(xb, wb, nullptr, nullptr, se, bias, out);
    } else {
        gemm_bt<false><<<grid, 256, 0, stream>>>(nullptr, nullptr, x, wq, se, bias, out);
    }
}

// Round 6
// 388.864 us; speedup vs baseline: 1.4053x; 1.4053x over previous
//
#include <hip/hip_runtime.h>

#define MT 16384   // B*T = 8*2048
#define NT 2048    // OUT
#define KT 2048    // IN
#define BM 128
#define BN 128
#define BK 64

typedef __attribute__((ext_vector_type(8))) short short8;     // 8 bf16 (4 VGPRs) MFMA A/B frag
typedef __attribute__((ext_vector_type(4))) float f32x4;      // MFMA C/D frag
typedef __attribute__((ext_vector_type(8))) unsigned short ushort8;
typedef __attribute__((ext_vector_type(4))) unsigned short ushort4v;

__device__ __forceinline__ unsigned short f32_bf16(float f) {
    union { float f; unsigned u; } v; v.f = f;
    return (unsigned short)((v.u + 0x7FFFu + ((v.u >> 16) & 1u)) >> 16);
}

// ---- merged preconvert: x (fp32->bf16) then w (int32->bf16), one dispatch ----

__global__ __launch_bounds__(256) void cvt_kernel(const float* __restrict__ x,
                                                  const int* __restrict__ w,
                                                  unsigned short* __restrict__ xb,
                                                  unsigned short* __restrict__ wb) {
    const int b = blockIdx.x;
    if (b < MT * KT / 2048) {
        size_t i = ((size_t)b * 256 + threadIdx.x) * 8;
        float4 v0 = *(const float4*)(x + i);
        float4 v1 = *(const float4*)(x + i + 4);
        ushort8 o;
        o[0] = f32_bf16(v0.x); o[1] = f32_bf16(v0.y); o[2] = f32_bf16(v0.z); o[3] = f32_bf16(v0.w);
        o[4] = f32_bf16(v1.x); o[5] = f32_bf16(v1.y); o[6] = f32_bf16(v1.z); o[7] = f32_bf16(v1.w);
        *(ushort8*)(xb + i) = o;
    } else {
        size_t i = ((size_t)(b - MT * KT / 2048) * 256 + threadIdx.x) * 8;
        int4 v0 = *(const int4*)(w + i);
        int4 v1 = *(const int4*)(w + i + 4);
        ushort8 o;
        o[0] = f32_bf16((float)v0.x); o[1] = f32_bf16((float)v0.y);
        o[2] = f32_bf16((float)v0.z); o[3] = f32_bf16((float)v0.w);
        o[4] = f32_bf16((float)v1.x); o[5] = f32_bf16((float)v1.y);
        o[6] = f32_bf16((float)v1.z); o[7] = f32_bf16((float)v1.w);
        *(ushort8*)(wb + i) = o;
    }
}

// ---- GEMM: C[m][n] = sum_k A[m][k] * W[n][k], epilogue *2^s_exp[n] + bias[n] ----
// R6 = R4 structure (both tiles LDS-staged; R5's B-register-bypass regressed
// 181->323 us: row-major B frag loads hit 16-64 cache lines/instr) + grid
// swizzle: N is now the FAST grid dim, so the 16 blocks sharing one 512 KB
// A-strip are dispatch-adjacent -> A staging hits L2 (drain ~200 cyc) instead
// of HBM (~900 cyc). B (8 MB) stays L2-resident regardless.
// LDS layout: [128 rows][8 chunks of 16B], chunk swizzled (R3-verified,
// SQ_LDS_BANK_CONFLICT 1.678e7 -> 0): logical (row,c) at slot row*8+((c+row)&7).

__device__ __forceinline__ int swz(int row, int c) {        // logical chunk -> slot
    return row * 8 + ((c + row) & 7);
}

template <bool PRE>
__global__ __launch_bounds__(256) void gemm_bt(
    const unsigned short* __restrict__ Abf, const unsigned short* __restrict__ Bbf,
    const float* __restrict__ Af32, const int* __restrict__ Wi32,
    const int* __restrict__ sexp, const float* __restrict__ bias,
    float* __restrict__ C)
{
    __shared__ unsigned short As[BM * BK];   // 16 KB
    __shared__ unsigned short Bs[BN * BK];   // 16 KB

    const int tid  = threadIdx.x;
    const int row0 = blockIdx.y * BM;   // M block (slow grid dim)
    const int col0 = blockIdx.x * BN;   // N block (fast: 16 consecutive blocks share A-strip)
    const int lane = tid & 63;
    const int wave = tid >> 6;
    const int wm = wave >> 1, wn = wave & 1;   // 2x2 waves, each 64x64
    const int q = lane >> 4, r = lane & 15;

    f32x4 acc[4][4] = {};

    for (int k0 = 0; k0 < KT; k0 += BK) {
        if constexpr (PRE) {
            // 1024 x 16B slots per matrix; slot s=(row,pos) holds logical chunk
            // (pos - row) & 7 of row s>>3; HW dest = wave-uniform base + lane*16.
            #pragma unroll
            for (int ii = 0; ii < 4; ++ii) {
                const int s   = tid + ii * 256;
                const int row = s >> 3;
                const int cg  = ((s & 7) - row) & 7;          // logical chunk stored here
                const unsigned short* ga =
                    Abf + (size_t)(row0 + row) * KT + k0 + cg * 8;
                __builtin_amdgcn_global_load_lds(
                    (const __attribute__((address_space(1))) unsigned int*)ga,
                    (__attribute__((address_space(3))) unsigned int*)(As + (size_t)(ii * 256 + wave * 64) * 8),
                    16, 0, 0);
                const unsigned short* gb =
                    Bbf + (size_t)(col0 + row) * KT + k0 + cg * 8;
                __builtin_amdgcn_global_load_lds(
                    (const __attribute__((address_space(1))) unsigned int*)gb,
                    (__attribute__((address_space(3))) unsigned int*)(Bs + (size_t)(ii * 256 + wave * 64) * 8),
                    16, 0, 0);
            }
        } else {
            // fused fallback: same swizzled layout, 8B granules (16 per row)
            #pragma unroll
            for (int ii = 0; ii < 8; ++ii) {
                const int s  = tid + ii * 256;
                const int rw = s >> 4, c4 = s & 15;
                const int ch = c4 >> 1, hf = c4 & 1;
                const int ps = ((ch + rw) & 7) * 8 + hf * 4;
                float4 v = *(const float4*)(Af32 + (size_t)(row0 + rw) * KT + k0 + c4 * 4);
                ushort4v oa;
                oa[0] = f32_bf16(v.x); oa[1] = f32_bf16(v.y);
                oa[2] = f32_bf16(v.z); oa[3] = f32_bf16(v.w);
                *(ushort4v*)(As + rw * BK + ps) = oa;
                int4 w4 = *(const int4*)(Wi32 + (size_t)(col0 + rw) * KT + k0 + c4 * 4);
                ushort4v ob;
                ob[0] = f32_bf16((float)w4.x); ob[1] = f32_bf16((float)w4.y);
                ob[2] = f32_bf16((float)w4.z); ob[3] = f32_bf16((float)w4.w);
                *(ushort4v*)(Bs + rw * BK + ps) = ob;
            }
        }
        __syncthreads();

        // two K=32 halves; frag element j = tile[row][k = h*32 + q*8 + j]
        #pragma unroll
        for (int h = 0; h < 2; ++h) {
            short8 a[4], b[4];
            #pragma unroll
            for (int i = 0; i < 4; ++i)
                a[i] = *(const short8*)(As + swz(wm * 64 + i * 16 + r, h * 4 + q) * 8);
            #pragma unroll
            for (int j = 0; j < 4; ++j)
                b[j] = *(const short8*)(Bs + swz(wn * 64 + j * 16 + r, h * 4 + q) * 8);
            #pragma unroll
            for (int i = 0; i < 4; ++i)
                #pragma unroll
                for (int j = 0; j < 4; ++j)
                    acc[i][j] = __builtin_amdgcn_mfma_f32_16x16x32_bf16(a[i], b[j], acc[i][j], 0, 0, 0);
        }
        __syncthreads();
    }

    // epilogue: C/D layout col = lane&15, row = (lane>>4)*4 + reg  [m89/m91-verified]
    #pragma unroll
    for (int j = 0; j < 4; ++j) {
        const int n  = col0 + wn * 64 + j * 16 + r;
        const float sc = ldexpf(1.0f, sexp[n]);   // exact power-of-two scale
        const float bs = bias[n];
        #pragma unroll
        for (int i = 0; i < 4; ++i) {
            const int m = row0 + wm * 64 + i * 16 + q * 4;
            float* cp = C + (size_t)m * NT + n;
            #pragma unroll
            for (int t = 0; t < 4; ++t)
                cp[(size_t)t * NT] = acc[i][j][t] * sc + bs;
        }
    }
}

extern "C" void kernel_launch(void* const* d_in, const int* in_sizes, int n_in,
                              void* d_out, int out_size, void* d_ws, size_t ws_size,
                              hipStream_t stream) {
    const float* x    = (const float*)d_in[0];
    const int*   wq   = (const int*)d_in[1];   // ternary {-1,0,1}, int32 per harness
    const int*   se   = (const int*)d_in[2];   // exponents [-8,0]
    const float* bias = (const float*)d_in[3];
    float* out = (float*)d_out;

    const size_t xb_elems = (size_t)MT * KT;   // 33554432
    const size_t wb_elems = (size_t)NT * KT;   // 4194304
    dim3 grid(NT / BN, MT / BM);               // (16, 128): N fast -> A-strip L2-hot

    if (ws_size >= (xb_elems + wb_elems) * sizeof(unsigned short)) {
        unsigned short* xb = (unsigned short*)d_ws;
        unsigned short* wb = xb + xb_elems;
        cvt_kernel<<<(int)((xb_elems + wb_elems) / (256 * 8)), 256, 0, stream>>>(x, wq, xb, wb);
        gemm_bt<true><<<grid, 256, 0, stream>>>(xb, wb, nullptr, nullptr, se, bias, out);
    } else {
        gemm_bt<false><<<grid, 256, 0, stream>>>(nullptr, nullptr, x, wq, se, bias, out);
    }
}